// Round 9
// baseline (3654.045 us; speedup 1.0000x reference)
//
#include <hip/hip_runtime.h>
#include <hip/hip_bf16.h>

#define B_ 128
#define T_ 1024
#define I_ 512
#define H_ 1024
#define O_ 512
#define NBLK 256
#define BUDGET 128

typedef __attribute__((ext_vector_type(8))) short bf16x8;
typedef __attribute__((ext_vector_type(4))) float f32x4;
typedef __attribute__((ext_vector_type(4))) unsigned u32x4;
typedef unsigned short u16;

__device__ __forceinline__ unsigned f2bf_u(float f) {
  union { float f; unsigned u; } v; v.f = f;
  return (v.u + 0x7fffu + ((v.u >> 16) & 1u)) >> 16;  // RNE bf16
}

__device__ __forceinline__ bf16x8 cvt8(const float* __restrict__ p) {
  union { bf16x8 v; unsigned u[4]; } r;
  const float4 f0 = *(const float4*)p;
  const float4 f1 = *(const float4*)(p + 4);
  r.u[0] = f2bf_u(f0.x) | (f2bf_u(f0.y) << 16);
  r.u[1] = f2bf_u(f0.z) | (f2bf_u(f0.w) << 16);
  r.u[2] = f2bf_u(f1.x) | (f2bf_u(f1.y) << 16);
  r.u[3] = f2bf_u(f1.z) | (f2bf_u(f1.w) << 16);
  return r.v;
}

__device__ __forceinline__ bf16x8 cvt8r(float4 f0, float4 f1) {
  union { bf16x8 v; unsigned u[4]; } r;
  r.u[0] = f2bf_u(f0.x) | (f2bf_u(f0.y) << 16);
  r.u[1] = f2bf_u(f0.z) | (f2bf_u(f0.w) << 16);
  r.u[2] = f2bf_u(f1.x) | (f2bf_u(f1.y) << 16);
  r.u[3] = f2bf_u(f1.z) | (f2bf_u(f1.w) << 16);
  return r.v;
}

// strip generation-tag sign bits -> valid bf16x8 fragment
__device__ __forceinline__ bf16x8 mk8v(u32x4 t) {
  union { u32x4 u; bf16x8 b; } v;
  v.u = t & 0x7fff7fffu;
  return v.b;
}

// fast path: L1-bypass load, served by the local XCD's L2
#define LDTF(dst, base, off)                                          \
  asm volatile("global_load_dwordx4 %0, %1, off offset:" #off " sc0"  \
               : "=v"(dst) : "v"(base))
// shadow path: coherence-point load (bypass L1+L2) — proven r4..r8
#define LDTS(dst, base, off)                                              \
  asm volatile("global_load_dwordx4 %0, %1, off offset:" #off " sc0 sc1" \
               : "=v"(dst) : "v"(base))

#define MFMA __builtin_amdgcn_mfma_f32_16x16x32_bf16

// one poll attempt: load 8 tile fragments from tb0, tag-check against tw
__device__ __forceinline__ bool try8(const u16* tb0, unsigned tw, bool fast,
                                     u32x4& t0, u32x4& t1, u32x4& t2,
                                     u32x4& t3, u32x4& t4, u32x4& t5,
                                     u32x4& t6, u32x4& t7) {
  const u16* tb4 = tb0 + 2048;
  if (fast) {
    LDTF(t0, tb0, 0);    LDTF(t1, tb0, 1024);
    LDTF(t2, tb0, 2048); LDTF(t3, tb0, 3072);
    LDTF(t4, tb4, 0);    LDTF(t5, tb4, 1024);
    LDTF(t6, tb4, 2048); LDTF(t7, tb4, 3072);
  } else {
    LDTS(t0, tb0, 0);    LDTS(t1, tb0, 1024);
    LDTS(t2, tb0, 2048); LDTS(t3, tb0, 3072);
    LDTS(t4, tb4, 0);    LDTS(t5, tb4, 1024);
    LDTS(t6, tb4, 2048); LDTS(t7, tb4, 3072);
  }
  asm volatile("s_waitcnt vmcnt(0)" ::: "memory");
  __builtin_amdgcn_sched_barrier(0);
  u32x4 m4 = (t0 ^ tw) | (t1 ^ tw) | (t2 ^ tw) | (t3 ^ tw) |
             (t4 ^ tw) | (t5 ^ tw) | (t6 ^ tw) | (t7 ^ tw);
  unsigned mm = m4.x | m4.y | m4.z | m4.w;
  return __all((mm & 0x80008000u) == 0u);
}

// Persistent RNN. Grid = 256 blocks x 256 threads (4 waves), 1 block/CU.
// Group g = blockIdx&7 (16 batch rows) — congruence classes, so with the
// default round-robin block->XCD mapping all 32 group members share one XCD.
// Slot s = blockIdx>>3 (32 hidden cols). W tile (96 KB) resident in LDS.
// h exchange: per-producer 1 KB tiles, DUAL copy:
//   fast  = plain store -> local L2, polled with sc0 (L1-bypass) loads
//   shadow= sc1 store   -> L3,       polled with sc1 loads (guaranteed)
// Consumers try fast for BUDGET iters; sticky fallback to shadow. Tags in
// bf16 sign bits (always 0 after relu) self-validate both copies =>
// correct under ANY block->XCD mapping; fast only affects speed.
__global__ __launch_bounds__(256, 1) void rnn_persist(
    const float* __restrict__ x, const float* __restrict__ Wih,
    const float* __restrict__ bih, const float* __restrict__ Whh,
    const float* __restrict__ bhh, const float* __restrict__ Who,
    const float* __restrict__ bho, u16* __restrict__ h0f,
    u16* __restrict__ h0s, u16* __restrict__ h1f, u16* __restrict__ h1s,
    float* __restrict__ out) {
  __shared__ u16 w_lds[192 * 32 * 8];  // 96 KB: [k-octet o][col c][8 bf16]
  __shared__ float red[2][256 * 9];    // 18 KB double-buffered reduce scratch
  __shared__ float bias_lds[32];

  const int tid = threadIdx.x;
  const int w = tid >> 6;
  const int lane = tid & 63;
  const int lr = lane & 15;
  const int kg = lane >> 4;
  const int g = (int)blockIdx.x & 7;    // congruence group (same XCD, likely)
  const int s = (int)blockIdx.x >> 3;   // column slot 0..31
  const int r0 = g * 16;
  const int c0 = s * 32;

  // ---- stage W tile [32 cols x 1536 K] into LDS ----
  for (int e = tid; e < 192 * 32; e += 256) {
    int o = e >> 5, c = e & 31;
    int k = o * 8, gc = c0 + c;
    const float* src = (k < H_) ? (Whh + (size_t)gc * H_ + k)
                                : (Wih + (size_t)gc * I_ + (k - H_));
    *(bf16x8*)&w_lds[e * 8] = cvt8(src);
  }
  if (tid < 32) bias_lds[tid] = bih[c0 + tid] + bhh[c0 + tid];
  __syncthreads();

  // LDS fragment bases (u16 units)
  const u16* wb_h = &w_lds[(((w * 32 + kg) * 32) + lr) * 8];
  const u16* wb_x = &w_lds[(((128 + w * 16 + kg) * 32) + lr) * 8];

  // per-lane offset inside a producer tile: row lr, k-octet kg (u16 units)
  const int loff = lr * 32 + kg * 8;
  // this wave consumes producer tiles w*8 .. w*8+7 of its group
  const size_t twave = ((size_t)(g * 32 + w * 8)) * 512;
  // this block produces tile (g,s); thread tid owns dword tid of it
  const size_t towndw = ((size_t)(g * 32 + s)) * 256 + tid;

  // reduce/store thread mapping (r7/r8-verified)
  const int rr = tid >> 4;           // row 0..15
  const int cpair = (tid & 15) * 2;  // col pair 0,2,..,30
  const int lane_r = (rr >> 2) << 4;
  const int reg_r = rr & 3;

  const f32x4 zero4 = {0.f, 0.f, 0.f, 0.f};
  f32x4 acc0, acc1;
  bool use_fast = true;

  // ---- prologue: x-part for t=0 into acc ----
  {
    const float* px = x + ((size_t)(r0 + lr) * T_) * I_ + w * 128 + kg * 8;
    acc0 = zero4;
    acc1 = zero4;
#pragma unroll
    for (int i = 0; i < 4; ++i) {
      bf16x8 a = cvt8(px + i * 32);
      acc0 = MFMA(a, *(const bf16x8*)(wb_x + i * 1024), acc0, 0, 0, 0);
      acc1 = MFMA(a, *(const bf16x8*)(wb_x + i * 1024 + 128), acc1, 0, 0, 0);
    }
  }

  for (int t = 0; t < T_; ++t) {
    const u16* hcF = (t & 1) ? h1f : h0f;
    const u16* hcS = (t & 1) ? h1s : h0s;
    u16* hnF = (t & 1) ? h0f : h1f;
    u16* hnS = (t & 1) ? h0s : h1s;
    const bool havex = (t + 1 < T_);

    u32x4 t0, t1, t2, t3, t4, t5, t6, t7;

    // 1: tag-poll h_t — fast (local L2) with budget, sticky shadow fallback
    if (t > 0) {
      const unsigned tw = ((t >> 1) & 1) ? 0x80008000u : 0u;
      bool got = false;
      if (use_fast) {
        const u16* fb = hcF + twave + loff;
#pragma unroll 1
        for (int it = 0; it < BUDGET; ++it) {
          if (try8(fb, tw, true, t0, t1, t2, t3, t4, t5, t6, t7)) {
            got = true;
            break;
          }
        }
        if (!got) use_fast = false;  // sticky: stop wasting fast polls
      }
      if (!got) {
        const u16* sb = hcS + twave + loff;
        while (!try8(sb, tw, false, t0, t1, t2, t3, t4, t5, t6, t7)) {
        }
      }
    }

    // 2: issue x loads for t+1 (after poll: not in the poll's vmcnt shadow)
    float4 xa0, xa1, xa2, xa3, xa4, xa5, xa6, xa7;
    const float* px =
        x + ((size_t)(r0 + lr) * T_ + (t + 1)) * I_ + w * 128 + kg * 8;
    if (havex) {
      xa0 = *(const float4*)(px);      xa1 = *(const float4*)(px + 4);
      xa2 = *(const float4*)(px + 32); xa3 = *(const float4*)(px + 36);
      xa4 = *(const float4*)(px + 64); xa5 = *(const float4*)(px + 68);
      xa6 = *(const float4*)(px + 96); xa7 = *(const float4*)(px + 100);
    }

    // 3: h-part MFMAs (fragments already in MFMA layout)
    if (t > 0) {
#define HS(i, tv)                                                          \
  acc0 = MFMA(mk8v(tv), *(const bf16x8*)(wb_h + (i)*1024), acc0, 0, 0, 0); \
  acc1 = MFMA(mk8v(tv), *(const bf16x8*)(wb_h + (i)*1024 + 128), acc1, 0, 0, 0);
      HS(0, t0) HS(1, t1) HS(2, t2) HS(3, t3)
      HS(4, t4) HS(5, t5) HS(6, t6) HS(7, t7)
#undef HS
    }

    // 4: cross-wave K-reduce, bias+relu, pack + tag, dual store
    float* redc = red[t & 1];
    *(f32x4*)&redc[(w * 64 + lane) * 9] = acc0;
    *(f32x4*)&redc[(w * 64 + lane) * 9 + 4] = acc1;
    __syncthreads();
    {
      const unsigned st = (((t + 1) >> 1) & 1) ? 0x80008000u : 0u;
      const int c1 = cpair + 1;
      const int l0 = lane_r | (cpair & 15), f0 = (cpair >> 4) * 4;
      const int l1 = lane_r | (c1 & 15), f1 = (c1 >> 4) * 4;
      float v0 = 0.f, v1 = 0.f;
#pragma unroll
      for (int ww = 0; ww < 4; ++ww) {
        v0 += redc[(ww * 64 + l0) * 9 + f0 + reg_r];
        v1 += redc[(ww * 64 + l1) * 9 + f1 + reg_r];
      }
      v0 += bias_lds[cpair];
      v1 += bias_lds[c1];
      v0 = v0 > 0.f ? v0 : 0.f;
      v1 = v1 > 0.f ? v1 : 0.f;
      unsigned pk = (f2bf_u(v0) | (f2bf_u(v1) << 16)) | st;
      *(volatile unsigned*)((unsigned*)hnF + towndw) = pk;  // fast: local L2
      __hip_atomic_store((unsigned*)hnS + towndw, pk, __ATOMIC_RELAXED,
                         __HIP_MEMORY_SCOPE_AGENT);         // shadow: L3
    }

    // 5: x-part for t+1 (off critical path; overlaps consumers' polls)
    f32x4 xacc0 = zero4, xacc1 = zero4;
    if (havex) {
      bf16x8 a0 = cvt8r(xa0, xa1), a1 = cvt8r(xa2, xa3);
      bf16x8 a2 = cvt8r(xa4, xa5), a3 = cvt8r(xa6, xa7);
      xacc0 = MFMA(a0, *(const bf16x8*)(wb_x), xacc0, 0, 0, 0);
      xacc1 = MFMA(a0, *(const bf16x8*)(wb_x + 128), xacc1, 0, 0, 0);
      xacc0 = MFMA(a1, *(const bf16x8*)(wb_x + 1024), xacc0, 0, 0, 0);
      xacc1 = MFMA(a1, *(const bf16x8*)(wb_x + 1152), xacc1, 0, 0, 0);
      xacc0 = MFMA(a2, *(const bf16x8*)(wb_x + 2048), xacc0, 0, 0, 0);
      xacc1 = MFMA(a2, *(const bf16x8*)(wb_x + 2176), xacc1, 0, 0, 0);
      xacc0 = MFMA(a3, *(const bf16x8*)(wb_x + 3072), xacc0, 0, 0, 0);
      xacc1 = MFMA(a3, *(const bf16x8*)(wb_x + 3200), xacc1, 0, 0, 0);
    }
    acc0 = xacc0;
    acc1 = xacc1;
  }

  // ---- output GEMM: poll h_T (tag 0), out = h @ Who^T + bho ----
  {
    u32x4 t0, t1, t2, t3, t4, t5, t6, t7;
    bool got = false;
    if (use_fast) {
      const u16* fb = h0f + twave + loff;
#pragma unroll 1
      for (int it = 0; it < BUDGET; ++it) {
        if (try8(fb, 0u, true, t0, t1, t2, t3, t4, t5, t6, t7)) {
          got = true;
          break;
        }
      }
    }
    if (!got) {
      const u16* sb = h0s + twave + loff;
      while (!try8(sb, 0u, false, t0, t1, t2, t3, t4, t5, t6, t7)) {
      }
    }
    const int c0o = s * 16;
    f32x4 o0 = zero4;
    const float* pwo = Who + (size_t)(c0o + lr) * H_ + w * 256 + kg * 8;
    o0 = MFMA(mk8v(t0), cvt8(pwo + 0), o0, 0, 0, 0);
    o0 = MFMA(mk8v(t1), cvt8(pwo + 32), o0, 0, 0, 0);
    o0 = MFMA(mk8v(t2), cvt8(pwo + 64), o0, 0, 0, 0);
    o0 = MFMA(mk8v(t3), cvt8(pwo + 96), o0, 0, 0, 0);
    o0 = MFMA(mk8v(t4), cvt8(pwo + 128), o0, 0, 0, 0);
    o0 = MFMA(mk8v(t5), cvt8(pwo + 160), o0, 0, 0, 0);
    o0 = MFMA(mk8v(t6), cvt8(pwo + 192), o0, 0, 0, 0);
    o0 = MFMA(mk8v(t7), cvt8(pwo + 224), o0, 0, 0, 0);
    float* redc = red[0];
    *(f32x4*)&redc[(w * 64 + lane) * 9] = o0;
    __syncthreads();
    const int cc = tid & 15;
    const int l0 = lane_r | cc;
    float v = 0.f;
#pragma unroll
    for (int ww = 0; ww < 4; ++ww) v += redc[(ww * 64 + l0) * 9 + reg_r];
    v += bho[c0o + cc];
    out[(size_t)(r0 + rr) * O_ + c0o + cc] = v;
  }
}

extern "C" void kernel_launch(void* const* d_in, const int* in_sizes, int n_in,
                              void* d_out, int out_size, void* d_ws,
                              size_t ws_size, hipStream_t stream) {
  const float* x = (const float*)d_in[0];
  const float* Wih = (const float*)d_in[1];
  const float* bih = (const float*)d_in[2];
  const float* Whh = (const float*)d_in[3];
  const float* bhh = (const float*)d_in[4];
  const float* Who = (const float*)d_in[5];
  const float* bho = (const float*)d_in[6];
  float* outp = (float*)d_out;

  const size_t HB = (size_t)B_ * H_ * 2;  // 256 KB per h copy
  char* ws = (char*)d_ws;
  u16* h0f = (u16*)(ws);           // h_even fast
  u16* h0s = (u16*)(ws + HB);      // h_even shadow
  u16* h1f = (u16*)(ws + 2 * HB);  // h_odd fast
  u16* h1s = (u16*)(ws + 3 * HB);  // h_odd shadow

  // h0: zeros, tag 0 (valid). h1: 0xFF (sign bits set => fails tag-0 check).
  hipMemsetAsync(ws, 0x00, 2 * HB, stream);
  hipMemsetAsync(ws + 2 * HB, 0xFF, 2 * HB, stream);

  void* args[] = {(void*)&x,   (void*)&Wih, (void*)&bih, (void*)&Whh,
                  (void*)&bhh, (void*)&Who, (void*)&bho, (void*)&h0f,
                  (void*)&h0s, (void*)&h1f, (void*)&h1s, (void*)&outp};
  hipLaunchCooperativeKernel((void*)rnn_persist, dim3(NBLK), dim3(256), args,
                             0, stream);
}

// Round 11
// 3500.354 us; speedup vs baseline: 1.0439x; 1.0439x over previous
//
#include <hip/hip_runtime.h>
#include <hip/hip_bf16.h>

#define B_ 128
#define T_ 1024
#define I_ 512
#define H_ 1024
#define O_ 512
#define NBLK 256

typedef __attribute__((ext_vector_type(8))) short bf16x8;
typedef __attribute__((ext_vector_type(4))) float f32x4;
typedef __attribute__((ext_vector_type(4))) unsigned u32x4;
typedef unsigned short u16;

__device__ __forceinline__ unsigned f2bf_u(float f) {
  union { float f; unsigned u; } v; v.f = f;
  return (v.u + 0x7fffu + ((v.u >> 16) & 1u)) >> 16;  // RNE bf16
}

__device__ __forceinline__ bf16x8 cvt8(const float* __restrict__ p) {
  union { bf16x8 v; unsigned u[4]; } r;
  const float4 f0 = *(const float4*)p;
  const float4 f1 = *(const float4*)(p + 4);
  r.u[0] = f2bf_u(f0.x) | (f2bf_u(f0.y) << 16);
  r.u[1] = f2bf_u(f0.z) | (f2bf_u(f0.w) << 16);
  r.u[2] = f2bf_u(f1.x) | (f2bf_u(f1.y) << 16);
  r.u[3] = f2bf_u(f1.z) | (f2bf_u(f1.w) << 16);
  return r.v;
}

__device__ __forceinline__ bf16x8 cvt8r(float4 f0, float4 f1) {
  union { bf16x8 v; unsigned u[4]; } r;
  r.u[0] = f2bf_u(f0.x) | (f2bf_u(f0.y) << 16);
  r.u[1] = f2bf_u(f0.z) | (f2bf_u(f0.w) << 16);
  r.u[2] = f2bf_u(f1.x) | (f2bf_u(f1.y) << 16);
  r.u[3] = f2bf_u(f1.z) | (f2bf_u(f1.w) << 16);
  return r.v;
}

// strip generation-tag sign bits -> valid bf16x8 fragment
__device__ __forceinline__ bf16x8 mk8v(u32x4 t) {
  union { u32x4 u; bf16x8 b; } v;
  v.u = t & 0x7fff7fffu;
  return v.b;
}

// coherence-point 16B load (sc0 sc1 = system scope, bypasses stale caches)
// — the r4..r9-proven exchange primitive. No other exchange path exists.
#define LDTS(dst, base, off)                                              \
  asm volatile("global_load_dwordx4 %0, %1, off offset:" #off " sc0 sc1" \
               : "=v"(dst) : "v"(base))

#define MFMA __builtin_amdgcn_mfma_f32_16x16x32_bf16

// counted vmcnt wait + scheduler fence (rule #18). vmcnt retires in-order
// (m135), so vmcnt(N) => all but the N newest VMEM ops have completed.
#define WAITV(N)                                            \
  do {                                                      \
    asm volatile("s_waitcnt vmcnt(" #N ")" ::: "memory");   \
    __builtin_amdgcn_sched_barrier(0);                      \
  } while (0)

#define ISSUE8(pb)                                                    \
  do {                                                                \
    const u16* _b4 = (pb) + 2048;                                     \
    LDTS(t0, (pb), 0);    LDTS(t1, (pb), 1024);                       \
    LDTS(t2, (pb), 2048); LDTS(t3, (pb), 3072);                       \
    LDTS(t4, _b4, 0);     LDTS(t5, _b4, 1024);                        \
    LDTS(t6, _b4, 2048);  LDTS(t7, _b4, 3072);                        \
  } while (0)

// Persistent RNN. Grid = 256 blocks x 256 threads (4 waves), 1 block/CU.
// Group g = blockIdx>>5 (16 batch rows); slot s = blockIdx&31 (32 hidden
// cols). W tile (96 KB) resident in LDS. h exchange: per-producer 1 KB tiles
// via sc1 (L3-coherent), generation tag in the (always-0 after relu) bf16
// sign bits. NEW vs r8: poll loads issued at the previous iteration's tail;
// per-tile counted-vmcnt streaming (tag-check + MFMA per tile as each load
// lands); parallel whole-round retries; own tile read from LDS (no self-RT).
__global__ __launch_bounds__(256, 1) void rnn_persist(
    const float* __restrict__ x, const float* __restrict__ Wih,
    const float* __restrict__ bih, const float* __restrict__ Whh,
    const float* __restrict__ bhh, const float* __restrict__ Who,
    const float* __restrict__ bho, u16* __restrict__ h0buf,
    u16* __restrict__ h1buf, float* __restrict__ out) {
  __shared__ u16 w_lds[192 * 32 * 8];  // 96 KB: [k-octet o][col c][8 bf16]
  __shared__ float red[2][256 * 9];    // 18 KB double-buffered reduce scratch
  __shared__ float bias_lds[32];
  __shared__ u16 h_own[16 * 32];       // block's own h tile, untagged (1 KB)

  const int tid = threadIdx.x;
  const int w = tid >> 6;
  const int lane = tid & 63;
  const int lr = lane & 15;
  const int kg = lane >> 4;
  const int g = (int)blockIdx.x >> 5;
  const int s = (int)blockIdx.x & 31;
  const int r0 = g * 16;
  const int c0 = s * 32;

  // ---- stage W tile [32 cols x 1536 K] into LDS ----
  for (int e = tid; e < 192 * 32; e += 256) {
    int o = e >> 5, c = e & 31;
    int k = o * 8, gc = c0 + c;
    const float* src = (k < H_) ? (Whh + (size_t)gc * H_ + k)
                                : (Wih + (size_t)gc * I_ + (k - H_));
    *(bf16x8*)&w_lds[e * 8] = cvt8(src);
  }
  if (tid < 32) bias_lds[tid] = bih[c0 + tid] + bhh[c0 + tid];
  __syncthreads();

  // LDS fragment bases (u16 units)
  const u16* wb_h = &w_lds[(((w * 32 + kg) * 32) + lr) * 8];
  const u16* wb_x = &w_lds[(((128 + w * 16 + kg) * 32) + lr) * 8];

  // per-lane offset inside a producer tile: row lr, k-octet kg (u16 units)
  const int loff = lr * 32 + kg * 8;
  // this wave consumes producer tiles w*8 .. w*8+7 of its group
  const size_t twave = ((size_t)(g * 32 + w * 8)) * 512;
  // this block produces tile (g,s); thread tid owns dword tid of it
  const size_t towndw = ((size_t)(g * 32 + s)) * 256 + tid;
  // own tile position within this wave's 8 consumed tiles (-1 if absent)
  const int ownj = ((s >> 3) == w) ? (s & 7) : -1;

  // reduce/store thread mapping (r7..r9-verified)
  const int rr = tid >> 4;           // row 0..15
  const int cpair = (tid & 15) * 2;  // col pair 0,2,..,30
  const int lane_r = (rr >> 2) << 4;
  const int reg_r = rr & 3;

  const f32x4 zero4 = {0.f, 0.f, 0.f, 0.f};
  f32x4 acc0, acc1;
  u32x4 t0, t1, t2, t3, t4, t5, t6, t7;  // poll registers, live across latch

  // ---- prologue: x-part for t=0 into acc ----
  {
    const float* px = x + ((size_t)(r0 + lr) * T_) * I_ + w * 128 + kg * 8;
    acc0 = zero4;
    acc1 = zero4;
#pragma unroll
    for (int i = 0; i < 4; ++i) {
      bf16x8 a = cvt8(px + i * 32);
      acc0 = MFMA(a, *(const bf16x8*)(wb_x + i * 1024), acc0, 0, 0, 0);
      acc1 = MFMA(a, *(const bf16x8*)(wb_x + i * 1024 + 128), acc1, 0, 0, 0);
    }
  }

// streaming pass-1 tile: counted wait, tag-check, MFMA (own tile from LDS)
#define PASS1(i, N)                                                           \
  WAITV(N);                                                                   \
  if ((i) == ownj) {                                                          \
    bf16x8 ov = *(const bf16x8*)&h_own[lr * 32 + kg * 8];                     \
    acc0 = MFMA(ov, *(const bf16x8*)(wb_h + (i) * 1024), acc0, 0, 0, 0);      \
    acc1 = MFMA(ov, *(const bf16x8*)(wb_h + (i) * 1024 + 128), acc1, 0, 0, 0);\
    done |= 1u << (i);                                                        \
  } else {                                                                    \
    unsigned _m = (t##i.x ^ tw) | (t##i.y ^ tw) | (t##i.z ^ tw) |             \
                  (t##i.w ^ tw);                                              \
    if (__all((_m & 0x80008000u) == 0u)) {                                    \
      acc0 = MFMA(mk8v(t##i), *(const bf16x8*)(wb_h + (i) * 1024), acc0, 0,   \
                  0, 0);                                                      \
      acc1 = MFMA(mk8v(t##i), *(const bf16x8*)(wb_h + (i) * 1024 + 128),      \
                  acc1, 0, 0, 0);                                             \
      done |= 1u << (i);                                                      \
    }                                                                         \
  }

// retry-round tile re-check (loads fully drained by WAITV(0))
#define RCHK(i)                                                               \
  if (!(done & (1u << (i)))) {                                                \
    unsigned _m = (t##i.x ^ tw) | (t##i.y ^ tw) | (t##i.z ^ tw) |             \
                  (t##i.w ^ tw);                                              \
    if (__all((_m & 0x80008000u) == 0u)) {                                    \
      acc0 = MFMA(mk8v(t##i), *(const bf16x8*)(wb_h + (i) * 1024), acc0, 0,   \
                  0, 0);                                                      \
      acc1 = MFMA(mk8v(t##i), *(const bf16x8*)(wb_h + (i) * 1024 + 128),      \
                  acc1, 0, 0, 0);                                             \
      done |= 1u << (i);                                                      \
    }                                                                         \
  }

  for (int t = 0; t < T_; ++t) {
    const u16* hc = (t & 1) ? h1buf : h0buf;
    u16* hn = (t & 1) ? h0buf : h1buf;
    const bool havex = (t + 1 < T_);

    // ---- PHASE A: consume h_t (loads issued at previous iteration's tail;
    //      queue = [S_prev, L0..L7] -> in-order counted waits are exact) ----
    if (t > 0) {
      const unsigned tw = ((t >> 1) & 1) ? 0x80008000u : 0u;
      unsigned done = 0;
      PASS1(0, 7) PASS1(1, 6) PASS1(2, 5) PASS1(3, 4)
      PASS1(4, 3) PASS1(5, 2) PASS1(6, 1) PASS1(7, 0)
      if (done != 0xFFu) {
        const u16* pb = hc + twave + loff;
        do {
          ISSUE8(pb);
          WAITV(0);
          RCHK(0) RCHK(1) RCHK(2) RCHK(3)
          RCHK(4) RCHK(5) RCHK(6) RCHK(7)
        } while (done != 0xFFu);
      }
    }

    // ---- PHASE B: issue x loads for t+1 ----
    float4 xa0, xa1, xa2, xa3, xa4, xa5, xa6, xa7;
    const float* px =
        x + ((size_t)(r0 + lr) * T_ + (t + 1)) * I_ + w * 128 + kg * 8;
    if (havex) {
      xa0 = *(const float4*)(px);      xa1 = *(const float4*)(px + 4);
      xa2 = *(const float4*)(px + 32); xa3 = *(const float4*)(px + 36);
      xa4 = *(const float4*)(px + 64); xa5 = *(const float4*)(px + 68);
      xa6 = *(const float4*)(px + 96); xa7 = *(const float4*)(px + 100);
    }

    // ---- PHASE C/D: cross-wave K-reduce, bias+relu, pack; store tagged
    //      tile (sc1) + write clean copy to LDS h_own; sync2 ----
    float* redc = red[t & 1];
    *(f32x4*)&redc[(w * 64 + lane) * 9] = acc0;
    *(f32x4*)&redc[(w * 64 + lane) * 9 + 4] = acc1;
    __syncthreads();  // sync1
    {
      const unsigned st = (((t + 1) >> 1) & 1) ? 0x80008000u : 0u;
      const int c1 = cpair + 1;
      const int l0 = lane_r | (cpair & 15), f0 = (cpair >> 4) * 4;
      const int l1 = lane_r | (c1 & 15), f1 = (c1 >> 4) * 4;
      float v0 = 0.f, v1 = 0.f;
#pragma unroll
      for (int ww = 0; ww < 4; ++ww) {
        v0 += redc[(ww * 64 + l0) * 9 + f0 + reg_r];
        v1 += redc[(ww * 64 + l1) * 9 + f1 + reg_r];
      }
      v0 += bias_lds[cpair];
      v1 += bias_lds[c1];
      v0 = v0 > 0.f ? v0 : 0.f;
      v1 = v1 > 0.f ? v1 : 0.f;
      unsigned pkc = f2bf_u(v0) | (f2bf_u(v1) << 16);  // clean (no tag)
      *(unsigned*)&h_own[rr * 32 + cpair] = pkc;       // LDS own-tile copy
      __hip_atomic_store((unsigned*)hn + towndw, pkc | st, __ATOMIC_RELAXED,
                         __HIP_MEMORY_SCOPE_AGENT);    // tagged sc1 store
    }
    __syncthreads();  // sync2: h_own complete before next step's reads

    // ---- PHASE E: x-part MFMAs for t+1 ----
    f32x4 xacc0 = zero4, xacc1 = zero4;
    if (havex) {
      bf16x8 a0 = cvt8r(xa0, xa1), a1 = cvt8r(xa2, xa3);
      bf16x8 a2 = cvt8r(xa4, xa5), a3 = cvt8r(xa6, xa7);
      xacc0 = MFMA(a0, *(const bf16x8*)(wb_x), xacc0, 0, 0, 0);
      xacc1 = MFMA(a0, *(const bf16x8*)(wb_x + 128), xacc1, 0, 0, 0);
      xacc0 = MFMA(a1, *(const bf16x8*)(wb_x + 1024), xacc0, 0, 0, 0);
      xacc1 = MFMA(a1, *(const bf16x8*)(wb_x + 1152), xacc1, 0, 0, 0);
      xacc0 = MFMA(a2, *(const bf16x8*)(wb_x + 2048), xacc0, 0, 0, 0);
      xacc1 = MFMA(a2, *(const bf16x8*)(wb_x + 2176), xacc1, 0, 0, 0);
      xacc0 = MFMA(a3, *(const bf16x8*)(wb_x + 3072), xacc0, 0, 0, 0);
      xacc1 = MFMA(a3, *(const bf16x8*)(wb_x + 3200), xacc1, 0, 0, 0);
    }
    acc0 = xacc0;
    acc1 = xacc1;

    // ---- TAIL: issue poll loads for h_{t+1} (in flight across the latch) ---
    {
      const u16* pb = hn + twave + loff;
      ISSUE8(pb);
    }
  }

  // ---- output GEMM: consume h_T (tag 0; loads already in flight) ----
  {
    const unsigned tw = 0u;
    const u16* pb = h0buf + twave + loff;
    WAITV(0);
    for (;;) {
      u32x4 m4 = (t0 ^ tw) | (t1 ^ tw) | (t2 ^ tw) | (t3 ^ tw) |
                 (t4 ^ tw) | (t5 ^ tw) | (t6 ^ tw) | (t7 ^ tw);
      unsigned mm = m4.x | m4.y | m4.z | m4.w;
      if (__all((mm & 0x80008000u) == 0u)) break;
      ISSUE8(pb);
      WAITV(0);
    }
    const int c0o = s * 16;
    f32x4 o0 = zero4;
    const float* pwo = Who + (size_t)(c0o + lr) * H_ + w * 256 + kg * 8;
    o0 = MFMA(mk8v(t0), cvt8(pwo + 0), o0, 0, 0, 0);
    o0 = MFMA(mk8v(t1), cvt8(pwo + 32), o0, 0, 0, 0);
    o0 = MFMA(mk8v(t2), cvt8(pwo + 64), o0, 0, 0, 0);
    o0 = MFMA(mk8v(t3), cvt8(pwo + 96), o0, 0, 0, 0);
    o0 = MFMA(mk8v(t4), cvt8(pwo + 128), o0, 0, 0, 0);
    o0 = MFMA(mk8v(t5), cvt8(pwo + 160), o0, 0, 0, 0);
    o0 = MFMA(mk8v(t6), cvt8(pwo + 192), o0, 0, 0, 0);
    o0 = MFMA(mk8v(t7), cvt8(pwo + 224), o0, 0, 0, 0);
    float* redc = red[0];
    *(f32x4*)&redc[(w * 64 + lane) * 9] = o0;
    __syncthreads();
    const int cc = tid & 15;
    const int l0 = lane_r | cc;
    float v = 0.f;
#pragma unroll
    for (int ww = 0; ww < 4; ++ww) v += redc[(ww * 64 + l0) * 9 + reg_r];
    v += bho[c0o + cc];
    out[(size_t)(r0 + rr) * O_ + c0o + cc] = v;
  }
}

extern "C" void kernel_launch(void* const* d_in, const int* in_sizes, int n_in,
                              void* d_out, int out_size, void* d_ws,
                              size_t ws_size, hipStream_t stream) {
  const float* x = (const float*)d_in[0];
  const float* Wih = (const float*)d_in[1];
  const float* bih = (const float*)d_in[2];
  const float* Whh = (const float*)d_in[3];
  const float* bhh = (const float*)d_in[4];
  const float* Who = (const float*)d_in[5];
  const float* bho = (const float*)d_in[6];
  float* outp = (float*)d_out;

  char* ws = (char*)d_ws;
  u16* h0b = (u16*)ws;                        // 256 KB, h_even (tile layout)
  u16* h1b = (u16*)(ws + B_ * H_ * 2);        // 256 KB, h_odd

  // h_0 = zeros with tag 0 (immediately valid). h1b = 0xFF: sign bits 1 =>
  // fails the tag-0 check for h_1 until truly written.
  hipMemsetAsync(h0b, 0x00, B_ * H_ * 2, stream);
  hipMemsetAsync(h1b, 0xFF, B_ * H_ * 2, stream);

  void* args[] = {(void*)&x,   (void*)&Wih, (void*)&bih, (void*)&Whh,
                  (void*)&bhh, (void*)&Who, (void*)&bho, (void*)&h0b,
                  (void*)&h1b, (void*)&outp};
  hipLaunchCooperativeKernel((void*)rnn_persist, dim3(NBLK), dim3(256), args,
                             0, stream);
}